// Round 11
// baseline (152.497 us; speedup 1.0000x reference)
//
#include <hip/hip_runtime.h>
#include <stdint.h>

#define EPSF 1e-5f

typedef __attribute__((ext_vector_type(8)))  short bh8;    // 8 bf16 = 4 VGPR
typedef __attribute__((ext_vector_type(16))) float fx16;   // 32x32 MFMA acc
typedef __attribute__((ext_vector_type(4)))  int   i32x4;

__device__ __forceinline__ int cvtpk(float a, float b) {
    int r;
    asm("v_cvt_pk_bf16_f32 %0, %1, %2" : "=v"(r) : "v"(a), "v"(b));
    return r;
}
__device__ __forceinline__ float fastrcp(float x) {
    float r;
    asm("v_rcp_f32 %0, %1" : "=v"(r) : "v"(x));
    return r;
}

// ---------------- K12: LN1 + QKV (head-sliced) + MFMA attention ----------------
// grid 256 = (b,h). block 512. Identical to the verified R10 kernel except the
// ctx store layout: now [b][s][40] (head h occupies cols h*10..h*10+9) so k3
// reads ctx rows exactly like x rows (no head gather).
__global__ __launch_bounds__(512) void k_qkv_attn(
    const float* __restrict__ x, const float* __restrict__ g, const float* __restrict__ be,
    const float* __restrict__ Wq, const float* __restrict__ bq,
    const float* __restrict__ Wk, const float* __restrict__ bk,
    const float* __restrict__ Wv, const float* __restrict__ bv,
    float* __restrict__ ctx)
{
    __shared__ __align__(16) char smem[83968];

    const int tid = threadIdx.x;
    const int bh = blockIdx.x;
    const int b  = bh >> 2;
    const int h  = bh & 3;               // block-uniform head index
    const int lane = tid & 63;
    const int wavei = tid >> 6;

    // ---- Phase A: stage x[b] (512 x 40 f32) ----
    float* sX = (float*)smem;
    {
        const float4* xb = (const float4*)(x + (size_t)b * 512 * 40);
        for (int idx = tid; idx < 5120; idx += 512) {
            float4 u = xb[idx];
            int fl = idx * 4;
            int r = fl / 40, c = fl - r * 40;
            sX[r * 41 + c] = u.x; sX[r * 41 + c + 1] = u.y;
            sX[r * 41 + c + 2] = u.z; sX[r * 41 + c + 3] = u.w;
        }
    }
    __syncthreads();

    // LN + QKV for row `tid`, head h only
    float s1 = 0.f, s2 = 0.f;
#pragma unroll 8
    for (int i = 0; i < 40; i++) { float v = sX[tid * 41 + i]; s1 += v; s2 += v * v; }
    const float mu = s1 * 0.025f;
    const float rs = rsqrtf(s2 * 0.025f - mu * mu + EPSF);

    float hrow[40];
#pragma unroll 4
    for (int i = 0; i < 40; i++)
        hrow[i] = (sX[tid * 41 + i] - mu) * rs * g[i] + be[i];

    float aq[10], ak[10], av[10];
#pragma unroll
    for (int c = 0; c < 10; c++) {
        aq[c] = bq[h * 10 + c]; ak[c] = bk[h * 10 + c]; av[c] = bv[h * 10 + c];
    }
#pragma unroll 2
    for (int i = 0; i < 40; i++) {
        const float hi = hrow[i];
        const float* wq = Wq + i * 40 + h * 10;   // uniform -> s_load
        const float* wk = Wk + i * 40 + h * 10;
        const float* wv = Wv + i * 40 + h * 10;
#pragma unroll
        for (int c = 0; c < 10; c++) {
            aq[c] += hi * wq[c]; ak[c] += hi * wk[c]; av[c] += hi * wv[c];
        }
    }
    const float cs = 1.4426950408889634f / 3.1622776601683795f;  // log2e/sqrt(10)
#pragma unroll
    for (int c = 0; c < 10; c++) aq[c] *= cs;

    __syncthreads();   // all sX reads done -> safe to overlay

    // ---- write K / V^T / Q into LDS ----
    char* sK  = smem;                    // [512] rows x 48B (32B data + pad)
    char* sVT = smem + 24576;            // [16] rows x 1040B (ones-row at d=10)
    char* sQ  = smem + 41216;            // [512] rows x 32B
    {
        int p0 = cvtpk(ak[0], ak[1]), p1 = cvtpk(ak[2], ak[3]);
        int p2 = cvtpk(ak[4], ak[5]), p3 = cvtpk(ak[6], ak[7]);
        int p4 = cvtpk(ak[8], ak[9]);
        i32x4* kd = (i32x4*)(sK + tid * 48);
        kd[0] = (i32x4){p0, p1, p2, p3};
        kd[1] = (i32x4){p4, 0, 0, 0};
    }
    {
        int p0 = cvtpk(aq[0], aq[1]), p1 = cvtpk(aq[2], aq[3]);
        int p2 = cvtpk(aq[4], aq[5]), p3 = cvtpk(aq[6], aq[7]);
        int p4 = cvtpk(aq[8], aq[9]);
        i32x4* qd = (i32x4*)(sQ + tid * 32);
        qd[0] = (i32x4){p0, p1, p2, p3};
        qd[1] = (i32x4){p4, 0, 0, 0};
    }
    {
        int p0 = cvtpk(av[0], av[1]), p1 = cvtpk(av[2], av[3]);
        int p2 = cvtpk(av[4], av[5]), p3 = cvtpk(av[6], av[7]);
        int p4 = cvtpk(av[8], av[9]);
        unsigned short* vb = (unsigned short*)sVT + tid;   // column tid, 520-short rows
        vb[0 * 520] = (unsigned short)(p0 & 0xffff);
        vb[1 * 520] = (unsigned short)((unsigned)p0 >> 16);
        vb[2 * 520] = (unsigned short)(p1 & 0xffff);
        vb[3 * 520] = (unsigned short)((unsigned)p1 >> 16);
        vb[4 * 520] = (unsigned short)(p2 & 0xffff);
        vb[5 * 520] = (unsigned short)((unsigned)p2 >> 16);
        vb[6 * 520] = (unsigned short)(p3 & 0xffff);
        vb[7 * 520] = (unsigned short)((unsigned)p3 >> 16);
        vb[8 * 520] = (unsigned short)(p4 & 0xffff);
        vb[9 * 520] = (unsigned short)((unsigned)p4 >> 16);
        vb[10 * 520] = 0x3F80;   // bf16(1.0) ones-row -> denominator
        vb[11 * 520] = 0; vb[12 * 520] = 0; vb[13 * 520] = 0;
        vb[14 * 520] = 0; vb[15 * 520] = 0;
    }
    __syncthreads();

    // ---- Phase B: attention (v13 math, all operands in LDS) ----
    const int krow = lane & 31, khalf = lane >> 5;
    const int vrow = lane & 15;
    const bool vzero = (lane & 16) != 0;

    bh8 qf0 = *(const bh8*)(sQ + (size_t)(wavei * 64 + (lane & 31)) * 32 + (lane >> 5) * 16);
    bh8 qf1 = *(const bh8*)(sQ + (size_t)(wavei * 64 + 32 + (lane & 31)) * 32 + (lane >> 5) * 16);

    fx16 acc0 = (fx16)(0.0f), acc1 = (fx16)(0.0f);

    for (int kt = 0; kt < 16; ++kt) {      // 32 keys / iter
        bh8 kf  = *(const bh8*)(sK + (kt * 32 + krow) * 48 + khalf * 16);
        bh8 vf0 = *(const bh8*)(sVT + vrow * 1040 + kt * 64 + khalf * 16);
        bh8 vf1 = *(const bh8*)(sVT + vrow * 1040 + kt * 64 + 32 + khalf * 16);
        if (vzero) { vf0 = (bh8)(short)0; vf1 = (bh8)(short)0; }
#pragma unroll
        for (int qt = 0; qt < 2; ++qt) {
            fx16 s = __builtin_amdgcn_mfma_f32_32x32x16_bf16(
                kf, qt ? qf1 : qf0, (fx16)(0.0f), 0, 0, 0);
            float e[16];
#pragma unroll
            for (int r = 0; r < 16; ++r) e[r] = __builtin_amdgcn_exp2f(s[r]);
            int c0 = cvtpk(e[0], e[1]),   c1 = cvtpk(e[2], e[3]);
            int c2 = cvtpk(e[4], e[5]),   c3 = cvtpk(e[6], e[7]);
            int c4 = cvtpk(e[8], e[9]),   c5 = cvtpk(e[10], e[11]);
            int c6 = cvtpk(e[12], e[13]), c7 = cvtpk(e[14], e[15]);
            asm("v_permlane32_swap_b32 %0, %1" : "+v"(c0), "+v"(c2));
            asm("v_permlane32_swap_b32 %0, %1" : "+v"(c1), "+v"(c3));
            asm("v_permlane32_swap_b32 %0, %1" : "+v"(c4), "+v"(c6));
            asm("v_permlane32_swap_b32 %0, %1" : "+v"(c5), "+v"(c7));
            union { i32x4 i; bh8 h; } lo, hi;
            lo.i = (i32x4){c0, c1, c2, c3};   // P[q][k 0..15 of this kt]
            hi.i = (i32x4){c4, c5, c6, c7};   // P[q][k 16..31]
            if (qt == 0) {
                acc0 = __builtin_amdgcn_mfma_f32_32x32x16_bf16(lo.h, vf0, acc0, 0, 0, 0);
                acc0 = __builtin_amdgcn_mfma_f32_32x32x16_bf16(hi.h, vf1, acc0, 0, 0, 0);
            } else {
                acc1 = __builtin_amdgcn_mfma_f32_32x32x16_bf16(lo.h, vf0, acc1, 0, 0, 0);
                acc1 = __builtin_amdgcn_mfma_f32_32x32x16_bf16(hi.h, vf1, acc1, 0, 0, 0);
            }
        }
    }

    // epilogue: col 10 = denominator; rcp; store to ctx[b][q][40] at cols h*10..
    const int d = lane & 31;
    const int qb = wavei * 64;
#pragma unroll
    for (int qt = 0; qt < 2; ++qt) {
        fx16 A = qt ? acc1 : acc0;
#pragma unroll
        for (int r = 0; r < 16; ++r) {
            float v = A[r];
            float ls = __shfl(v, (lane & 32) | 10, 64);
            float o = v * fastrcp(ls);
            if (d < 10) {
                int q = qb + qt * 32 + (r & 3) + 8 * (r >> 2) + 4 * (lane >> 5);
                ctx[((size_t)b * 512 + q) * 40 + h * 10 + d] = o;
            }
        }
    }
}

// ---------------- K3 v2: Wo + residual + LN2 + FFN + residual ----------------
// grid 512 x 64 (one wave). Thread = one full row: LN2 stats, GELU, and all
// three matmuls are thread-local (zero cross-thread exchange). Weights read
// via block-uniform s_load (9.6KB, L2-hot) -- no weight LDS staging. LDS only
// for coalescing x/ctx in and out (41-pad = conflict-free rows). ctx is
// [b][s][40] (written by k12), so it stages exactly like x.
__global__ __launch_bounds__(64) void k_out_ffn(
    const float* __restrict__ ctx, const float* __restrict__ x,
    const float* __restrict__ Wo, const float* __restrict__ bo,
    const float* __restrict__ g2, const float* __restrict__ bt2,
    const float* __restrict__ W1, const float* __restrict__ b1,
    const float* __restrict__ W2, const float* __restrict__ b2,
    float* __restrict__ out)
{
    __shared__ float sX[64][41];
    __shared__ float sC[64][41];

    const int tid = threadIdx.x;
    const float4* xblk = (const float4*)(x + (size_t)blockIdx.x * 64 * 40);
    const float4* cblk = (const float4*)(ctx + (size_t)blockIdx.x * 64 * 40);
    for (int idx = tid; idx < 640; idx += 64) {
        float4 u = xblk[idx];
        float4 v = cblk[idx];
        int fl = idx * 4;
        int r = fl / 40, c = fl - r * 40;
        sX[r][c] = u.x; sX[r][c + 1] = u.y; sX[r][c + 2] = u.z; sX[r][c + 3] = u.w;
        sC[r][c] = v.x; sC[r][c + 1] = v.y; sC[r][c + 2] = v.z; sC[r][c + 3] = v.w;
    }
    __syncthreads();   // single wave -> compiles to waitcnt

    // acc = x + bo + ctx @ Wo
    float acc[40];
#pragma unroll 8
    for (int c = 0; c < 40; c++) acc[c] = sX[tid][c] + bo[c];
#pragma unroll 2
    for (int i = 0; i < 40; i++) {
        const float ci = sC[tid][i];
        const float* wp = Wo + i * 40;       // uniform -> s_load
#pragma unroll
        for (int c = 0; c < 40; c++) acc[c] += ci * wp[c];
    }

    // LN2 (thread-local)
    float s1 = 0.f, s2 = 0.f;
#pragma unroll 8
    for (int c = 0; c < 40; c++) { s1 += acc[c]; s2 += acc[c] * acc[c]; }
    const float mu = s1 * 0.025f;
    const float rs = rsqrtf(s2 * 0.025f - mu * mu + EPSF);

    float h2[40];
#pragma unroll 4
    for (int c = 0; c < 40; c++)
        h2[c] = (acc[c] - mu) * rs * g2[c] + bt2[c];

    // inter = gelu(h2 @ W1 + b1)
    float it[20];
#pragma unroll
    for (int j = 0; j < 20; j++) it[j] = b1[j];
#pragma unroll 2
    for (int i = 0; i < 40; i++) {
        const float hi = h2[i];
        const float* wp = W1 + i * 20;       // uniform -> s_load
#pragma unroll
        for (int j = 0; j < 20; j++) it[j] += hi * wp[j];
    }
#pragma unroll 4
    for (int j = 0; j < 20; j++) {
        float t = it[j];
        it[j] = 0.5f * t * (1.0f + erff(t * 0.70710678118654752f));
    }

    // out = acc + b2 + inter @ W2
#pragma unroll 8
    for (int c = 0; c < 40; c++) acc[c] += b2[c];
#pragma unroll 2
    for (int i = 0; i < 20; i++) {
        const float ii = it[i];
        const float* wp = W2 + i * 40;       // uniform -> s_load
#pragma unroll
        for (int c = 0; c < 40; c++) acc[c] += ii * wp[c];
    }

    __syncthreads();   // sC reads done -> reuse as out-repack buffer
#pragma unroll 8
    for (int c = 0; c < 40; c++) sC[tid][c] = acc[c];
    __syncthreads();

    float4* oblk = (float4*)(out + (size_t)blockIdx.x * 64 * 40);
    for (int idx = tid; idx < 640; idx += 64) {
        int fl = idx * 4;
        int r = fl / 40, c = fl - r * 40;
        float4 u;
        u.x = sC[r][c]; u.y = sC[r][c + 1]; u.z = sC[r][c + 2]; u.w = sC[r][c + 3];
        oblk[idx] = u;
    }
}

extern "C" void kernel_launch(void* const* d_in, const int* in_sizes, int n_in,
                              void* d_out, int out_size, void* d_ws, size_t ws_size,
                              hipStream_t stream)
{
    const float* x   = (const float*)d_in[0];
    const float* g1  = (const float*)d_in[1];
    const float* be1 = (const float*)d_in[2];
    const float* Wq  = (const float*)d_in[3];
    const float* bq  = (const float*)d_in[4];
    const float* Wk  = (const float*)d_in[5];
    const float* bk  = (const float*)d_in[6];
    const float* Wv  = (const float*)d_in[7];
    const float* bv  = (const float*)d_in[8];
    const float* Wo  = (const float*)d_in[9];
    const float* bo  = (const float*)d_in[10];
    const float* g2  = (const float*)d_in[11];
    const float* bt2 = (const float*)d_in[12];
    const float* W1  = (const float*)d_in[13];
    const float* b1  = (const float*)d_in[14];
    const float* W2  = (const float*)d_in[15];
    const float* b2  = (const float*)d_in[16];

    float* ctx = (float*)d_ws;   // [B][S][40] f32 = 5.24 MB

    k_qkv_attn<<<256, 512, 0, stream>>>(x, g1, be1, Wq, bq, Wk, bk, Wv, bv, ctx);
    k_out_ffn<<<512, 64, 0, stream>>>(ctx, x, Wo, bo, g2, bt2, W1, b1, W2, b2,
                                      (float*)d_out);
}

// Round 12
// 133.301 us; speedup vs baseline: 1.1440x; 1.1440x over previous
//
#include <hip/hip_runtime.h>
#include <stdint.h>

#define EPSF 1e-5f

typedef __attribute__((ext_vector_type(8)))  short bh8;    // 8 bf16 = 4 VGPR
typedef __attribute__((ext_vector_type(16))) float fx16;   // 32x32 MFMA acc
typedef __attribute__((ext_vector_type(4)))  int   i32x4;

__device__ __forceinline__ int cvtpk(float a, float b) {
    int r;
    asm("v_cvt_pk_bf16_f32 %0, %1, %2" : "=v"(r) : "v"(a), "v"(b));
    return r;
}
__device__ __forceinline__ float fastrcp(float x) {
    float r;
    asm("v_rcp_f32 %0, %1" : "=v"(r) : "v"(x));
    return r;
}

// ---------------- K12: LN1 + QKV (head-sliced) + MFMA attention ----------------
// grid 256 = (b,h). block 512. Verified in R11. ctx layout [b][s][40]
// (head h occupies cols h*10..h*10+9).
__global__ __launch_bounds__(512) void k_qkv_attn(
    const float* __restrict__ x, const float* __restrict__ g, const float* __restrict__ be,
    const float* __restrict__ Wq, const float* __restrict__ bq,
    const float* __restrict__ Wk, const float* __restrict__ bk,
    const float* __restrict__ Wv, const float* __restrict__ bv,
    float* __restrict__ ctx)
{
    __shared__ __align__(16) char smem[83968];

    const int tid = threadIdx.x;
    const int bh = blockIdx.x;
    const int b  = bh >> 2;
    const int h  = bh & 3;               // block-uniform head index
    const int lane = tid & 63;
    const int wavei = tid >> 6;

    // ---- Phase A: stage x[b] (512 x 40 f32) ----
    float* sX = (float*)smem;
    {
        const float4* xb = (const float4*)(x + (size_t)b * 512 * 40);
        for (int idx = tid; idx < 5120; idx += 512) {
            float4 u = xb[idx];
            int fl = idx * 4;
            int r = fl / 40, c = fl - r * 40;
            sX[r * 41 + c] = u.x; sX[r * 41 + c + 1] = u.y;
            sX[r * 41 + c + 2] = u.z; sX[r * 41 + c + 3] = u.w;
        }
    }
    __syncthreads();

    // LN + QKV for row `tid`, head h only
    float s1 = 0.f, s2 = 0.f;
#pragma unroll 8
    for (int i = 0; i < 40; i++) { float v = sX[tid * 41 + i]; s1 += v; s2 += v * v; }
    const float mu = s1 * 0.025f;
    const float rs = rsqrtf(s2 * 0.025f - mu * mu + EPSF);

    float hrow[40];
#pragma unroll 4
    for (int i = 0; i < 40; i++)
        hrow[i] = (sX[tid * 41 + i] - mu) * rs * g[i] + be[i];

    float aq[10], ak[10], av[10];
#pragma unroll
    for (int c = 0; c < 10; c++) {
        aq[c] = bq[h * 10 + c]; ak[c] = bk[h * 10 + c]; av[c] = bv[h * 10 + c];
    }
#pragma unroll 2
    for (int i = 0; i < 40; i++) {
        const float hi = hrow[i];
        const float* wq = Wq + i * 40 + h * 10;   // uniform -> s_load
        const float* wk = Wk + i * 40 + h * 10;
        const float* wv = Wv + i * 40 + h * 10;
#pragma unroll
        for (int c = 0; c < 10; c++) {
            aq[c] += hi * wq[c]; ak[c] += hi * wk[c]; av[c] += hi * wv[c];
        }
    }
    const float cs = 1.4426950408889634f / 3.1622776601683795f;  // log2e/sqrt(10)
#pragma unroll
    for (int c = 0; c < 10; c++) aq[c] *= cs;

    __syncthreads();   // all sX reads done -> safe to overlay

    // ---- write K / V^T / Q into LDS ----
    char* sK  = smem;                    // [512] rows x 48B (32B data + pad)
    char* sVT = smem + 24576;            // [16] rows x 1040B (ones-row at d=10)
    char* sQ  = smem + 41216;            // [512] rows x 32B
    {
        int p0 = cvtpk(ak[0], ak[1]), p1 = cvtpk(ak[2], ak[3]);
        int p2 = cvtpk(ak[4], ak[5]), p3 = cvtpk(ak[6], ak[7]);
        int p4 = cvtpk(ak[8], ak[9]);
        i32x4* kd = (i32x4*)(sK + tid * 48);
        kd[0] = (i32x4){p0, p1, p2, p3};
        kd[1] = (i32x4){p4, 0, 0, 0};
    }
    {
        int p0 = cvtpk(aq[0], aq[1]), p1 = cvtpk(aq[2], aq[3]);
        int p2 = cvtpk(aq[4], aq[5]), p3 = cvtpk(aq[6], aq[7]);
        int p4 = cvtpk(aq[8], aq[9]);
        i32x4* qd = (i32x4*)(sQ + tid * 32);
        qd[0] = (i32x4){p0, p1, p2, p3};
        qd[1] = (i32x4){p4, 0, 0, 0};
    }
    {
        int p0 = cvtpk(av[0], av[1]), p1 = cvtpk(av[2], av[3]);
        int p2 = cvtpk(av[4], av[5]), p3 = cvtpk(av[6], av[7]);
        int p4 = cvtpk(av[8], av[9]);
        unsigned short* vb = (unsigned short*)sVT + tid;   // column tid, 520-short rows
        vb[0 * 520] = (unsigned short)(p0 & 0xffff);
        vb[1 * 520] = (unsigned short)((unsigned)p0 >> 16);
        vb[2 * 520] = (unsigned short)(p1 & 0xffff);
        vb[3 * 520] = (unsigned short)((unsigned)p1 >> 16);
        vb[4 * 520] = (unsigned short)(p2 & 0xffff);
        vb[5 * 520] = (unsigned short)((unsigned)p2 >> 16);
        vb[6 * 520] = (unsigned short)(p3 & 0xffff);
        vb[7 * 520] = (unsigned short)((unsigned)p3 >> 16);
        vb[8 * 520] = (unsigned short)(p4 & 0xffff);
        vb[9 * 520] = (unsigned short)((unsigned)p4 >> 16);
        vb[10 * 520] = 0x3F80;   // bf16(1.0) ones-row -> denominator
        vb[11 * 520] = 0; vb[12 * 520] = 0; vb[13 * 520] = 0;
        vb[14 * 520] = 0; vb[15 * 520] = 0;
    }
    __syncthreads();

    // ---- Phase B: attention (v13 math, all operands in LDS) ----
    const int krow = lane & 31, khalf = lane >> 5;
    const int vrow = lane & 15;
    const bool vzero = (lane & 16) != 0;

    bh8 qf0 = *(const bh8*)(sQ + (size_t)(wavei * 64 + (lane & 31)) * 32 + (lane >> 5) * 16);
    bh8 qf1 = *(const bh8*)(sQ + (size_t)(wavei * 64 + 32 + (lane & 31)) * 32 + (lane >> 5) * 16);

    fx16 acc0 = (fx16)(0.0f), acc1 = (fx16)(0.0f);

    for (int kt = 0; kt < 16; ++kt) {      // 32 keys / iter
        bh8 kf  = *(const bh8*)(sK + (kt * 32 + krow) * 48 + khalf * 16);
        bh8 vf0 = *(const bh8*)(sVT + vrow * 1040 + kt * 64 + khalf * 16);
        bh8 vf1 = *(const bh8*)(sVT + vrow * 1040 + kt * 64 + 32 + khalf * 16);
        if (vzero) { vf0 = (bh8)(short)0; vf1 = (bh8)(short)0; }
#pragma unroll
        for (int qt = 0; qt < 2; ++qt) {
            fx16 s = __builtin_amdgcn_mfma_f32_32x32x16_bf16(
                kf, qt ? qf1 : qf0, (fx16)(0.0f), 0, 0, 0);
            float e[16];
#pragma unroll
            for (int r = 0; r < 16; ++r) e[r] = __builtin_amdgcn_exp2f(s[r]);
            int c0 = cvtpk(e[0], e[1]),   c1 = cvtpk(e[2], e[3]);
            int c2 = cvtpk(e[4], e[5]),   c3 = cvtpk(e[6], e[7]);
            int c4 = cvtpk(e[8], e[9]),   c5 = cvtpk(e[10], e[11]);
            int c6 = cvtpk(e[12], e[13]), c7 = cvtpk(e[14], e[15]);
            asm("v_permlane32_swap_b32 %0, %1" : "+v"(c0), "+v"(c2));
            asm("v_permlane32_swap_b32 %0, %1" : "+v"(c1), "+v"(c3));
            asm("v_permlane32_swap_b32 %0, %1" : "+v"(c4), "+v"(c6));
            asm("v_permlane32_swap_b32 %0, %1" : "+v"(c5), "+v"(c7));
            union { i32x4 i; bh8 h; } lo, hi;
            lo.i = (i32x4){c0, c1, c2, c3};   // P[q][k 0..15 of this kt]
            hi.i = (i32x4){c4, c5, c6, c7};   // P[q][k 16..31]
            if (qt == 0) {
                acc0 = __builtin_amdgcn_mfma_f32_32x32x16_bf16(lo.h, vf0, acc0, 0, 0, 0);
                acc0 = __builtin_amdgcn_mfma_f32_32x32x16_bf16(hi.h, vf1, acc0, 0, 0, 0);
            } else {
                acc1 = __builtin_amdgcn_mfma_f32_32x32x16_bf16(lo.h, vf0, acc1, 0, 0, 0);
                acc1 = __builtin_amdgcn_mfma_f32_32x32x16_bf16(hi.h, vf1, acc1, 0, 0, 0);
            }
        }
    }

    // epilogue: col 10 = denominator; rcp; store to ctx[b][q][40] at cols h*10..
    const int d = lane & 31;
    const int qb = wavei * 64;
#pragma unroll
    for (int qt = 0; qt < 2; ++qt) {
        fx16 A = qt ? acc1 : acc0;
#pragma unroll
        for (int r = 0; r < 16; ++r) {
            float v = A[r];
            float ls = __shfl(v, (lane & 32) | 10, 64);
            float o = v * fastrcp(ls);
            if (d < 10) {
                int q = qb + qt * 32 + (r & 3) + 8 * (r >> 2) + 4 * (lane >> 5);
                ctx[((size_t)b * 512 + q) * 40 + h * 10 + d] = o;
            }
        }
    }
}

// ---------------- K3: Wo + residual + LN2 + FFN + residual ----------------
// grid 512 x 256 (proven R10 structure: 2048 waves = 2/SIMD). Block = 64 rows;
// wave = col-slice, lane = row. Only diff vs R10: ctx is [b][s][40], so its
// staging is a straight row copy identical to x (gather/repack deleted).
__global__ __launch_bounds__(256) void k_out_ffn(
    const float* __restrict__ ctx, const float* __restrict__ x,
    const float* __restrict__ Wo, const float* __restrict__ bo,
    const float* __restrict__ g2, const float* __restrict__ bt2,
    const float* __restrict__ W1, const float* __restrict__ b1,
    const float* __restrict__ W2, const float* __restrict__ b2,
    float* __restrict__ out)
{
    __shared__ float sWo[40][48];
    __shared__ float sW1[40][32];
    __shared__ float sW2[20][48];
    __shared__ float sBo[40], sG2[40], sBt2[40], sB1[20], sB2[40];
    __shared__ float sCtx[64][41];
    __shared__ float sH[64][41];
    __shared__ float sIt[64][21];
    __shared__ float sSum[64][4], sSum2[64][4];

    const int tid = threadIdx.x;
    for (int idx = tid; idx < 1600; idx += 256) {
        int i = idx / 40, j = idx % 40;
        sWo[i][(j / 10) * 12 + (j % 10)] = Wo[idx];
    }
    for (int idx = tid; idx < 800; idx += 256) {
        {
            int i = idx / 20, j = idx % 20;
            sW1[i][(j / 5) * 8 + (j % 5)] = W1[idx];
        }
        {
            int i = idx / 40, j = idx % 40;
            sW2[i][(j / 10) * 12 + (j % 10)] = W2[idx];
        }
    }
    if (tid < 40) { sBo[tid] = bo[tid]; sG2[tid] = g2[tid]; sBt2[tid] = bt2[tid]; sB2[tid] = b2[tid]; }
    if (tid < 20) sB1[tid] = b1[tid];

    const float4* cblk = (const float4*)(ctx + (size_t)blockIdx.x * 64 * 40);
    for (int idx = tid; idx < 640; idx += 256) {
        float4 v = cblk[idx];
        int fl = idx * 4;
        int r = fl / 40, c = fl - r * 40;
        sCtx[r][c] = v.x; sCtx[r][c + 1] = v.y; sCtx[r][c + 2] = v.z; sCtx[r][c + 3] = v.w;
    }
    const float4* xblk = (const float4*)(x + (size_t)blockIdx.x * 64 * 40);
    for (int idx = tid; idx < 640; idx += 256) {
        float4 w = xblk[idx];
        int fl = idx * 4;
        int r = fl / 40, c = fl - r * 40;
        sH[r][c] = w.x; sH[r][c + 1] = w.y; sH[r][c + 2] = w.z; sH[r][c + 3] = w.w;
    }
    __syncthreads();

    const int lane = tid & 63;
    const int wv = tid >> 6;
    const int j0 = wv * 10;

    float acc[10];
#pragma unroll
    for (int j = 0; j < 10; j++) acc[j] = sBo[j0 + j] + sH[lane][j0 + j];
#pragma unroll 8
    for (int i = 0; i < 40; i++) {
        const float ci = sCtx[lane][i];
        const float4* wrow = (const float4*)&sWo[i][wv * 12];
        float4 w0 = wrow[0], w1 = wrow[1], w2 = wrow[2];
        acc[0] += ci * w0.x; acc[1] += ci * w0.y; acc[2] += ci * w0.z; acc[3] += ci * w0.w;
        acc[4] += ci * w1.x; acc[5] += ci * w1.y; acc[6] += ci * w1.z; acc[7] += ci * w1.w;
        acc[8] += ci * w2.x; acc[9] += ci * w2.y;
    }
    {
        float s1 = 0.f, s2 = 0.f;
#pragma unroll
        for (int j = 0; j < 10; j++) { s1 += acc[j]; s2 += acc[j] * acc[j]; }
        sSum[lane][wv] = s1; sSum2[lane][wv] = s2;
    }
    __syncthreads();
    const float mu = (sSum[lane][0] + sSum[lane][1] + sSum[lane][2] + sSum[lane][3]) * 0.025f;
    const float ex2 = (sSum2[lane][0] + sSum2[lane][1] + sSum2[lane][2] + sSum2[lane][3]) * 0.025f;
    const float rs = rsqrtf(ex2 - mu * mu + EPSF);
#pragma unroll
    for (int j = 0; j < 10; j++)
        sH[lane][j0 + j] = (acc[j] - mu) * rs * sG2[j0 + j] + sBt2[j0 + j];
    __syncthreads();

    const int f0 = wv * 5;
    float it[5];
#pragma unroll
    for (int j = 0; j < 5; j++) it[j] = sB1[f0 + j];
#pragma unroll 8
    for (int i = 0; i < 40; i++) {
        const float hi = sH[lane][i];
        const float4* wrow = (const float4*)&sW1[i][wv * 8];
        float4 w0 = wrow[0], w1 = wrow[1];
        it[0] += hi * w0.x; it[1] += hi * w0.y; it[2] += hi * w0.z; it[3] += hi * w0.w;
        it[4] += hi * w1.x;
    }
#pragma unroll
    for (int j = 0; j < 5; j++) {
        float t = it[j];
        sIt[lane][f0 + j] = 0.5f * t * (1.0f + erff(t * 0.70710678118654752f));
    }
    __syncthreads();

    float o[10];
#pragma unroll
    for (int j = 0; j < 10; j++) o[j] = acc[j] + sB2[j0 + j];
#pragma unroll 4
    for (int i = 0; i < 20; i++) {
        const float ii = sIt[lane][i];
        const float4* wrow = (const float4*)&sW2[i][wv * 12];
        float4 w0 = wrow[0], w1 = wrow[1], w2 = wrow[2];
        o[0] += ii * w0.x; o[1] += ii * w0.y; o[2] += ii * w0.z; o[3] += ii * w0.w;
        o[4] += ii * w1.x; o[5] += ii * w1.y; o[6] += ii * w1.z; o[7] += ii * w1.w;
        o[8] += ii * w2.x; o[9] += ii * w2.y;
    }
#pragma unroll
    for (int j = 0; j < 10; j++) sCtx[lane][j0 + j] = o[j];
    __syncthreads();

    float4* oblk = (float4*)(out + (size_t)blockIdx.x * 64 * 40);
    for (int idx = tid; idx < 640; idx += 256) {
        int fl = idx * 4;
        int r = fl / 40, c = fl - r * 40;
        float4 u;
        u.x = sCtx[r][c]; u.y = sCtx[r][c + 1]; u.z = sCtx[r][c + 2]; u.w = sCtx[r][c + 3];
        oblk[idx] = u;
    }
}

extern "C" void kernel_launch(void* const* d_in, const int* in_sizes, int n_in,
                              void* d_out, int out_size, void* d_ws, size_t ws_size,
                              hipStream_t stream)
{
    const float* x   = (const float*)d_in[0];
    const float* g1  = (const float*)d_in[1];
    const float* be1 = (const float*)d_in[2];
    const float* Wq  = (const float*)d_in[3];
    const float* bq  = (const float*)d_in[4];
    const float* Wk  = (const float*)d_in[5];
    const float* bk  = (const float*)d_in[6];
    const float* Wv  = (const float*)d_in[7];
    const float* bv  = (const float*)d_in[8];
    const float* Wo  = (const float*)d_in[9];
    const float* bo  = (const float*)d_in[10];
    const float* g2  = (const float*)d_in[11];
    const float* bt2 = (const float*)d_in[12];
    const float* W1  = (const float*)d_in[13];
    const float* b1  = (const float*)d_in[14];
    const float* W2  = (const float*)d_in[15];
    const float* b2  = (const float*)d_in[16];

    float* ctx = (float*)d_ws;   // [B][S][40] f32 = 5.24 MB

    k_qkv_attn<<<256, 512, 0, stream>>>(x, g1, be1, Wq, bq, Wk, bk, Wv, bv, ctx);
    k_out_ffn<<<512, 256, 0, stream>>>(ctx, x, Wo, bo, g2, bt2, W1, b1, W2, b2,
                                       (float*)d_out);
}

// Round 13
// 128.812 us; speedup vs baseline: 1.1839x; 1.0348x over previous
//
#include <hip/hip_runtime.h>
#include <stdint.h>

#define EPSF 1e-5f

typedef __attribute__((ext_vector_type(8)))  short bh8;    // 8 bf16 = 4 VGPR
typedef __attribute__((ext_vector_type(16))) float fx16;   // 32x32 MFMA acc
typedef __attribute__((ext_vector_type(4)))  int   i32x4;

__device__ __forceinline__ int cvtpk(float a, float b) {
    int r;
    asm("v_cvt_pk_bf16_f32 %0, %1, %2" : "=v"(r) : "v"(a), "v"(b));
    return r;
}
__device__ __forceinline__ float fastrcp(float x) {
    float r;
    asm("v_rcp_f32 %0, %1" : "=v"(r) : "v"(x));
    return r;
}

// ---------------- K12: LN1 + QKV (head-sliced) + MFMA attention ----------------
// grid 256 = (b,h). block 512. (R10-verified, 129.7us total.)
// Block computes LN+QKV for all 512 rows of batch b, head h ONLY (weight
// slice is block-uniform -> s_load), writes K/V^T/Q into LDS, then runs
// MFMA attention. Q/K/V never touch HBM. ctx layout [bh][512][10] --
// coalescing-optimal for the per-head writer (R12 measured the
// head-interleaved [b][s][40] alternative at +3.6us from scattered stores).
// LDS: phase A sX[512][41] f32 = 84KB; phase B overlays:
//   sK 512x48B = 24576 | sVT 16x1040B = 16640 | sQ 512x32B = 16384.
__global__ __launch_bounds__(512) void k_qkv_attn(
    const float* __restrict__ x, const float* __restrict__ g, const float* __restrict__ be,
    const float* __restrict__ Wq, const float* __restrict__ bq,
    const float* __restrict__ Wk, const float* __restrict__ bk,
    const float* __restrict__ Wv, const float* __restrict__ bv,
    float* __restrict__ ctx)
{
    __shared__ __align__(16) char smem[83968];

    const int tid = threadIdx.x;
    const int bh = blockIdx.x;
    const int b  = bh >> 2;
    const int h  = bh & 3;               // block-uniform head index
    const int lane = tid & 63;
    const int wavei = tid >> 6;

    // ---- Phase A: stage x[b] (512 x 40 f32) ----
    float* sX = (float*)smem;
    {
        const float4* xb = (const float4*)(x + (size_t)b * 512 * 40);
        for (int idx = tid; idx < 5120; idx += 512) {
            float4 u = xb[idx];
            int fl = idx * 4;
            int r = fl / 40, c = fl - r * 40;
            sX[r * 41 + c] = u.x; sX[r * 41 + c + 1] = u.y;
            sX[r * 41 + c + 2] = u.z; sX[r * 41 + c + 3] = u.w;
        }
    }
    __syncthreads();

    // LN + QKV for row `tid`, head h only
    float s1 = 0.f, s2 = 0.f;
#pragma unroll 8
    for (int i = 0; i < 40; i++) { float v = sX[tid * 41 + i]; s1 += v; s2 += v * v; }
    const float mu = s1 * 0.025f;
    const float rs = rsqrtf(s2 * 0.025f - mu * mu + EPSF);

    float hrow[40];
#pragma unroll 4
    for (int i = 0; i < 40; i++)
        hrow[i] = (sX[tid * 41 + i] - mu) * rs * g[i] + be[i];

    float aq[10], ak[10], av[10];
#pragma unroll
    for (int c = 0; c < 10; c++) {
        aq[c] = bq[h * 10 + c]; ak[c] = bk[h * 10 + c]; av[c] = bv[h * 10 + c];
    }
#pragma unroll 2
    for (int i = 0; i < 40; i++) {
        const float hi = hrow[i];
        const float* wq = Wq + i * 40 + h * 10;   // uniform -> s_load
        const float* wk = Wk + i * 40 + h * 10;
        const float* wv = Wv + i * 40 + h * 10;
#pragma unroll
        for (int c = 0; c < 10; c++) {
            aq[c] += hi * wq[c]; ak[c] += hi * wk[c]; av[c] += hi * wv[c];
        }
    }
    const float cs = 1.4426950408889634f / 3.1622776601683795f;  // log2e/sqrt(10)
#pragma unroll
    for (int c = 0; c < 10; c++) aq[c] *= cs;

    __syncthreads();   // all sX reads done -> safe to overlay

    // ---- write K / V^T / Q into LDS ----
    char* sK  = smem;                    // [512] rows x 48B (32B data + pad)
    char* sVT = smem + 24576;            // [16] rows x 1040B (ones-row at d=10)
    char* sQ  = smem + 41216;            // [512] rows x 32B
    {
        int p0 = cvtpk(ak[0], ak[1]), p1 = cvtpk(ak[2], ak[3]);
        int p2 = cvtpk(ak[4], ak[5]), p3 = cvtpk(ak[6], ak[7]);
        int p4 = cvtpk(ak[8], ak[9]);
        i32x4* kd = (i32x4*)(sK + tid * 48);
        kd[0] = (i32x4){p0, p1, p2, p3};
        kd[1] = (i32x4){p4, 0, 0, 0};
    }
    {
        int p0 = cvtpk(aq[0], aq[1]), p1 = cvtpk(aq[2], aq[3]);
        int p2 = cvtpk(aq[4], aq[5]), p3 = cvtpk(aq[6], aq[7]);
        int p4 = cvtpk(aq[8], aq[9]);
        i32x4* qd = (i32x4*)(sQ + tid * 32);
        qd[0] = (i32x4){p0, p1, p2, p3};
        qd[1] = (i32x4){p4, 0, 0, 0};
    }
    {
        int p0 = cvtpk(av[0], av[1]), p1 = cvtpk(av[2], av[3]);
        int p2 = cvtpk(av[4], av[5]), p3 = cvtpk(av[6], av[7]);
        int p4 = cvtpk(av[8], av[9]);
        unsigned short* vb = (unsigned short*)sVT + tid;   // column tid, 520-short rows
        vb[0 * 520] = (unsigned short)(p0 & 0xffff);
        vb[1 * 520] = (unsigned short)((unsigned)p0 >> 16);
        vb[2 * 520] = (unsigned short)(p1 & 0xffff);
        vb[3 * 520] = (unsigned short)((unsigned)p1 >> 16);
        vb[4 * 520] = (unsigned short)(p2 & 0xffff);
        vb[5 * 520] = (unsigned short)((unsigned)p2 >> 16);
        vb[6 * 520] = (unsigned short)(p3 & 0xffff);
        vb[7 * 520] = (unsigned short)((unsigned)p3 >> 16);
        vb[8 * 520] = (unsigned short)(p4 & 0xffff);
        vb[9 * 520] = (unsigned short)((unsigned)p4 >> 16);
        vb[10 * 520] = 0x3F80;   // bf16(1.0) ones-row -> denominator
        vb[11 * 520] = 0; vb[12 * 520] = 0; vb[13 * 520] = 0;
        vb[14 * 520] = 0; vb[15 * 520] = 0;
    }
    __syncthreads();

    // ---- Phase B: attention (all operands in LDS) ----
    const int krow = lane & 31, khalf = lane >> 5;
    const int vrow = lane & 15;
    const bool vzero = (lane & 16) != 0;

    bh8 qf0 = *(const bh8*)(sQ + (size_t)(wavei * 64 + (lane & 31)) * 32 + (lane >> 5) * 16);
    bh8 qf1 = *(const bh8*)(sQ + (size_t)(wavei * 64 + 32 + (lane & 31)) * 32 + (lane >> 5) * 16);

    fx16 acc0 = (fx16)(0.0f), acc1 = (fx16)(0.0f);

    for (int kt = 0; kt < 16; ++kt) {      // 32 keys / iter
        bh8 kf  = *(const bh8*)(sK + (kt * 32 + krow) * 48 + khalf * 16);
        bh8 vf0 = *(const bh8*)(sVT + vrow * 1040 + kt * 64 + khalf * 16);
        bh8 vf1 = *(const bh8*)(sVT + vrow * 1040 + kt * 64 + 32 + khalf * 16);
        if (vzero) { vf0 = (bh8)(short)0; vf1 = (bh8)(short)0; }
#pragma unroll
        for (int qt = 0; qt < 2; ++qt) {
            fx16 s = __builtin_amdgcn_mfma_f32_32x32x16_bf16(
                kf, qt ? qf1 : qf0, (fx16)(0.0f), 0, 0, 0);
            float e[16];
#pragma unroll
            for (int r = 0; r < 16; ++r) e[r] = __builtin_amdgcn_exp2f(s[r]);
            int c0 = cvtpk(e[0], e[1]),   c1 = cvtpk(e[2], e[3]);
            int c2 = cvtpk(e[4], e[5]),   c3 = cvtpk(e[6], e[7]);
            int c4 = cvtpk(e[8], e[9]),   c5 = cvtpk(e[10], e[11]);
            int c6 = cvtpk(e[12], e[13]), c7 = cvtpk(e[14], e[15]);
            asm("v_permlane32_swap_b32 %0, %1" : "+v"(c0), "+v"(c2));
            asm("v_permlane32_swap_b32 %0, %1" : "+v"(c1), "+v"(c3));
            asm("v_permlane32_swap_b32 %0, %1" : "+v"(c4), "+v"(c6));
            asm("v_permlane32_swap_b32 %0, %1" : "+v"(c5), "+v"(c7));
            union { i32x4 i; bh8 h; } lo, hi;
            lo.i = (i32x4){c0, c1, c2, c3};   // P[q][k 0..15 of this kt]
            hi.i = (i32x4){c4, c5, c6, c7};   // P[q][k 16..31]
            if (qt == 0) {
                acc0 = __builtin_amdgcn_mfma_f32_32x32x16_bf16(lo.h, vf0, acc0, 0, 0, 0);
                acc0 = __builtin_amdgcn_mfma_f32_32x32x16_bf16(hi.h, vf1, acc0, 0, 0, 0);
            } else {
                acc1 = __builtin_amdgcn_mfma_f32_32x32x16_bf16(lo.h, vf0, acc1, 0, 0, 0);
                acc1 = __builtin_amdgcn_mfma_f32_32x32x16_bf16(hi.h, vf1, acc1, 0, 0, 0);
            }
        }
    }

    // epilogue: col 10 = denominator; rcp; store to ctx[bh][q][10]
    const int d = lane & 31;
    const int qb = wavei * 64;
#pragma unroll
    for (int qt = 0; qt < 2; ++qt) {
        fx16 A = qt ? acc1 : acc0;
#pragma unroll
        for (int r = 0; r < 16; ++r) {
            float v = A[r];
            float ls = __shfl(v, (lane & 32) | 10, 64);
            float o = v * fastrcp(ls);
            if (d < 10) {
                int q = qb + qt * 32 + (r & 3) + 8 * (r >> 2) + 4 * (lane >> 5);
                ctx[((size_t)bh * 512 + q) * 10 + d] = o;
            }
        }
    }
}

// ---------------- K3: Wo + residual + LN2 + FFN + residual ----------------
// grid 512 x 256 (R10-verified). Block = 64 rows; wave = col-slice, lane = row.
// ctx [bh][512][10] gathered into sCtx[64][40] per block.
__global__ __launch_bounds__(256) void k_out_ffn(
    const float* __restrict__ ctx, const float* __restrict__ x,
    const float* __restrict__ Wo, const float* __restrict__ bo,
    const float* __restrict__ g2, const float* __restrict__ bt2,
    const float* __restrict__ W1, const float* __restrict__ b1,
    const float* __restrict__ W2, const float* __restrict__ b2,
    float* __restrict__ out)
{
    __shared__ float sWo[40][48];
    __shared__ float sW1[40][32];
    __shared__ float sW2[20][48];
    __shared__ float sBo[40], sG2[40], sBt2[40], sB1[20], sB2[40];
    __shared__ float sCtx[64][41];
    __shared__ float sH[64][41];
    __shared__ float sIt[64][21];
    __shared__ float sSum[64][4], sSum2[64][4];

    const int tid = threadIdx.x;
    for (int idx = tid; idx < 1600; idx += 256) {
        int i = idx / 40, j = idx % 40;
        sWo[i][(j / 10) * 12 + (j % 10)] = Wo[idx];
    }
    for (int idx = tid; idx < 800; idx += 256) {
        {
            int i = idx / 20, j = idx % 20;
            sW1[i][(j / 5) * 8 + (j % 5)] = W1[idx];
        }
        {
            int i = idx / 40, j = idx % 40;
            sW2[i][(j / 10) * 12 + (j % 10)] = W2[idx];
        }
    }
    if (tid < 40) { sBo[tid] = bo[tid]; sG2[tid] = g2[tid]; sBt2[tid] = bt2[tid]; sB2[tid] = b2[tid]; }
    if (tid < 20) sB1[tid] = b1[tid];

    const int row0 = blockIdx.x * 64;
    const int b = row0 >> 9, s0 = row0 & 511;

    for (int idx = tid; idx < 640; idx += 256) {
        const int hh = idx / 160, f = idx - hh * 160;
        float4 u = *(const float4*)(ctx + ((size_t)((b * 4 + hh) * 512 + s0)) * 10 + f * 4);
        const int fo = f * 4;
        float e[4] = {u.x, u.y, u.z, u.w};
#pragma unroll
        for (int t = 0; t < 4; t++) {
            const int fe = fo + t;
            const int r = fe / 10, c = fe - r * 10;
            sCtx[r][hh * 10 + c] = e[t];
        }
    }
    const float4* xblk = (const float4*)(x + (size_t)blockIdx.x * 64 * 40);
    for (int idx = tid; idx < 640; idx += 256) {
        float4 w = xblk[idx];
        int fl = idx * 4;
        int r = fl / 40, c = fl - r * 40;
        sH[r][c] = w.x; sH[r][c + 1] = w.y; sH[r][c + 2] = w.z; sH[r][c + 3] = w.w;
    }
    __syncthreads();

    const int lane = tid & 63;
    const int wv = tid >> 6;
    const int j0 = wv * 10;

    float acc[10];
#pragma unroll
    for (int j = 0; j < 10; j++) acc[j] = sBo[j0 + j] + sH[lane][j0 + j];
#pragma unroll 8
    for (int i = 0; i < 40; i++) {
        const float ci = sCtx[lane][i];
        const float4* wrow = (const float4*)&sWo[i][wv * 12];
        float4 w0 = wrow[0], w1 = wrow[1], w2 = wrow[2];
        acc[0] += ci * w0.x; acc[1] += ci * w0.y; acc[2] += ci * w0.z; acc[3] += ci * w0.w;
        acc[4] += ci * w1.x; acc[5] += ci * w1.y; acc[6] += ci * w1.z; acc[7] += ci * w1.w;
        acc[8] += ci * w2.x; acc[9] += ci * w2.y;
    }
    {
        float s1 = 0.f, s2 = 0.f;
#pragma unroll
        for (int j = 0; j < 10; j++) { s1 += acc[j]; s2 += acc[j] * acc[j]; }
        sSum[lane][wv] = s1; sSum2[lane][wv] = s2;
    }
    __syncthreads();
    const float mu = (sSum[lane][0] + sSum[lane][1] + sSum[lane][2] + sSum[lane][3]) * 0.025f;
    const float ex2 = (sSum2[lane][0] + sSum2[lane][1] + sSum2[lane][2] + sSum2[lane][3]) * 0.025f;
    const float rs = rsqrtf(ex2 - mu * mu + EPSF);
#pragma unroll
    for (int j = 0; j < 10; j++)
        sH[lane][j0 + j] = (acc[j] - mu) * rs * sG2[j0 + j] + sBt2[j0 + j];
    __syncthreads();

    const int f0 = wv * 5;
    float it[5];
#pragma unroll
    for (int j = 0; j < 5; j++) it[j] = sB1[f0 + j];
#pragma unroll 8
    for (int i = 0; i < 40; i++) {
        const float hi = sH[lane][i];
        const float4* wrow = (const float4*)&sW1[i][wv * 8];
        float4 w0 = wrow[0], w1 = wrow[1];
        it[0] += hi * w0.x; it[1] += hi * w0.y; it[2] += hi * w0.z; it[3] += hi * w0.w;
        it[4] += hi * w1.x;
    }
#pragma unroll
    for (int j = 0; j < 5; j++) {
        float t = it[j];
        sIt[lane][f0 + j] = 0.5f * t * (1.0f + erff(t * 0.70710678118654752f));
    }
    __syncthreads();

    float o[10];
#pragma unroll
    for (int j = 0; j < 10; j++) o[j] = acc[j] + sB2[j0 + j];
#pragma unroll 4
    for (int i = 0; i < 20; i++) {
        const float ii = sIt[lane][i];
        const float4* wrow = (const float4*)&sW2[i][wv * 12];
        float4 w0 = wrow[0], w1 = wrow[1], w2 = wrow[2];
        o[0] += ii * w0.x; o[1] += ii * w0.y; o[2] += ii * w0.z; o[3] += ii * w0.w;
        o[4] += ii * w1.x; o[5] += ii * w1.y; o[6] += ii * w1.z; o[7] += ii * w1.w;
        o[8] += ii * w2.x; o[9] += ii * w2.y;
    }
#pragma unroll
    for (int j = 0; j < 10; j++) sCtx[lane][j0 + j] = o[j];
    __syncthreads();

    float4* oblk = (float4*)(out + (size_t)blockIdx.x * 64 * 40);
    for (int idx = tid; idx < 640; idx += 256) {
        int fl = idx * 4;
        int r = fl / 40, c = fl - r * 40;
        float4 u;
        u.x = sCtx[r][c]; u.y = sCtx[r][c + 1]; u.z = sCtx[r][c + 2]; u.w = sCtx[r][c + 3];
        oblk[idx] = u;
    }
}

extern "C" void kernel_launch(void* const* d_in, const int* in_sizes, int n_in,
                              void* d_out, int out_size, void* d_ws, size_t ws_size,
                              hipStream_t stream)
{
    const float* x   = (const float*)d_in[0];
    const float* g1  = (const float*)d_in[1];
    const float* be1 = (const float*)d_in[2];
    const float* Wq  = (const float*)d_in[3];
    const float* bq  = (const float*)d_in[4];
    const float* Wk  = (const float*)d_in[5];
    const float* bk  = (const float*)d_in[6];
    const float* Wv  = (const float*)d_in[7];
    const float* bv  = (const float*)d_in[8];
    const float* Wo  = (const float*)d_in[9];
    const float* bo  = (const float*)d_in[10];
    const float* g2  = (const float*)d_in[11];
    const float* bt2 = (const float*)d_in[12];
    const float* W1  = (const float*)d_in[13];
    const float* b1  = (const float*)d_in[14];
    const float* W2  = (const float*)d_in[15];
    const float* b2  = (const float*)d_in[16];

    float* ctx = (float*)d_ws;   // [B*H][S][10] f32 = 5.24 MB

    k_qkv_attn<<<256, 512, 0, stream>>>(x, g1, be1, Wq, bq, Wk, bk, Wv, bv, ctx);
    k_out_ffn<<<512, 256, 0, stream>>>(ctx, x, Wo, bo, g2, bt2, W1, b1, W2, b2,
                                       (float*)d_out);
}